// Round 4
// baseline (52.670 us; speedup 1.0000x reference)
//
#include <hip/hip_runtime.h>
#include <hip/hip_bf16.h>
#include <stdint.h>

#define D_DIM 256
#define K_CTR 1024
#define B_ROWS 16384
#define BM 32

typedef __bf16 bf16x8 __attribute__((ext_vector_type(8)));
typedef float f32x4 __attribute__((ext_vector_type(4)));

static __device__ __forceinline__ unsigned short f2bf(float f) {
    return __builtin_bit_cast(unsigned short, __float2bfloat16(f));
}

// Prep: centers f32 -> bf16 fragment-major + c_sq f32. Grid 256 x 256thr, 4 rows/block.
// Chunk (colgrp, kk, hk, col&15) at byte colgrp*8192 + kk*1024 + hk*256 + (col&15)*16
// -> main's wave B-load (lane l = hk*16+lr) is one contiguous 1KB dwordx4 at l*16.
__global__ __launch_bounds__(256) void rbf_prep(const float* __restrict__ centers,
                                                unsigned short* __restrict__ cbf,
                                                float* __restrict__ csq) {
    const int w = threadIdx.x >> 6;
    const int l = threadIdx.x & 63;
    const int row = blockIdx.x * 4 + w;
    const float4 v = *reinterpret_cast<const float4*>(centers + row * D_DIM + l * 4);
    float s = v.x * v.x + v.y * v.y + v.z * v.z + v.w * v.w;
    ushort4 p;
    p.x = f2bf(v.x); p.y = f2bf(v.y); p.z = f2bf(v.z); p.w = f2bf(v.w);
    char* dst = reinterpret_cast<char*>(cbf)
              + (row >> 4) * 8192 + (l >> 3) * 1024 + ((l >> 1) & 3) * 256
              + (row & 15) * 16 + (l & 1) * 8;
    *reinterpret_cast<ushort4*>(dst) = p;
    #pragma unroll
    for (int off = 1; off < 64; off <<= 1) s += __shfl_xor(s, off);
    if (l == 0) csq[row] = s;
}

// Main: block = 512 thr (8 waves) = 32 rows x 1024 cols -> one contiguous 128KB
// output region per block, written in ascending column order.
// wr = w>>2 picks 16-row half; wc = w&3 is the FAST column dimension.
__global__ __launch_bounds__(512, 4) void rbf_main(const float* __restrict__ x,
                                                   const unsigned short* __restrict__ cbf,
                                                   const float* __restrict__ csq,
                                                   const float* __restrict__ betas,
                                                   float* __restrict__ out) {
    __shared__ __align__(16) unsigned short As[BM * D_DIM];  // 16 KB, XOR-swizzled
    __shared__ float xs_lds[BM];

    const int tid = threadIdx.x;
    const int w = tid >> 6;
    const int l = tid & 63;
    const int wr = w >> 2;
    const int wc = w & 3;
    // XCD-chunked bijective swizzle: XCD i gets 64 consecutive strips (8MB out range)
    const int strip = (blockIdx.x & 7) * 64 + (blockIdx.x >> 3);
    const int row0 = strip * BM;

    // ---- Stage A strip (bf16, swizzled) + x_sq: 4 iters, wave w -> row i*8+w ----
    #pragma unroll
    for (int i = 0; i < 4; ++i) {
        const int r = i * 8 + w;
        const float4 v = *reinterpret_cast<const float4*>(x + (row0 + r) * D_DIM + l * 4);
        float s = v.x * v.x + v.y * v.y + v.z * v.z + v.w * v.w;
        ushort4 p;
        p.x = f2bf(v.x); p.y = f2bf(v.y); p.z = f2bf(v.z); p.w = f2bf(v.w);
        const unsigned boff = (unsigned)((r * 512 + l * 8) ^ ((r & 7) << 4));
        *reinterpret_cast<ushort4*>(reinterpret_cast<char*>(As) + boff) = p;
        #pragma unroll
        for (int off = 1; off < 64; off <<= 1) s += __shfl_xor(s, off);
        if (l == 0) xs_lds[r] = s;
    }
    __syncthreads();

    const int hk = l >> 4;
    const int lr = l & 15;
    const int r = wr * 16 + lr;          // this lane's output row within strip

    // ---- Hoist this wave's A fragments (16-row half): 8 frags = 32 VGPR ----
    bf16x8 a[8];
    #pragma unroll
    for (int kk = 0; kk < 8; ++kk) {
        const unsigned boff = (unsigned)((r * 512 + kk * 64 + hk * 16) ^ ((r & 7) << 4));
        a[kk] = *reinterpret_cast<const bf16x8*>(reinterpret_cast<const char*>(As) + boff);
    }
    const float xs = xs_lds[r];
    const size_t orow = (size_t)(row0 + r) * K_CTR;

    // ---- 8 col tiles of 128; wc is fast col dim -> block writes cols ascending ----
    #pragma unroll 1
    for (int ct = 0; ct < 8; ++ct) {
        const int colbase = ct * 128 + wc * 32;
        const char* bbase = reinterpret_cast<const char*>(cbf) + (colbase >> 4) * 8192 + l * 16;

        f32x4 acc[2] = {};
        bf16x8 b[2][4];
        // half 0: kk 0..3 (8 x 1KB coalesced loads in flight)
        #pragma unroll
        for (int kk = 0; kk < 4; ++kk)
            #pragma unroll
            for (int n = 0; n < 2; ++n)
                b[n][kk] = *reinterpret_cast<const bf16x8*>(bbase + n * 8192 + kk * 1024);
        #pragma unroll
        for (int kk = 0; kk < 4; ++kk)
            #pragma unroll
            for (int n = 0; n < 2; ++n)
                acc[n] = __builtin_amdgcn_mfma_f32_16x16x32_bf16(b[n][kk], a[kk], acc[n], 0, 0, 0);
        // half 1: kk 4..7
        #pragma unroll
        for (int kk = 0; kk < 4; ++kk)
            #pragma unroll
            for (int n = 0; n < 2; ++n)
                b[n][kk] = *reinterpret_cast<const bf16x8*>(bbase + n * 8192 + (kk + 4) * 1024);
        #pragma unroll
        for (int kk = 0; kk < 4; ++kk)
            #pragma unroll
            for (int n = 0; n < 2; ++n)
                acc[n] = __builtin_amdgcn_mfma_f32_16x16x32_bf16(b[n][kk], a[kk + 4], acc[n], 0, 0, 0);

        // ---- Epilogue: exp(-beta*(xsq+csq-2*cross)); 16B stores, L2-aggregated ----
        #pragma unroll
        for (int n = 0; n < 2; ++n) {
            const int c0 = colbase + n * 16 + hk * 4;
            const f32x4 cs = *reinterpret_cast<const f32x4*>(csq + c0);
            const f32x4 bt = *reinterpret_cast<const f32x4*>(betas + c0);
            f32x4 rv;
            #pragma unroll
            for (int j = 0; j < 4; ++j)
                rv[j] = __expf(-bt[j] * (xs + cs[j] - 2.0f * acc[n][j]));
            *reinterpret_cast<f32x4*>(out + orow + c0) = rv;
        }
    }
}

extern "C" void kernel_launch(void* const* d_in, const int* in_sizes, int n_in,
                              void* d_out, int out_size, void* d_ws, size_t ws_size,
                              hipStream_t stream) {
    const float* x       = (const float*)d_in[0];
    const float* centers = (const float*)d_in[1];
    const float* betas   = (const float*)d_in[2];
    float* out = (float*)d_out;

    unsigned short* cbf = (unsigned short*)d_ws;                      // 512 KB fragment-major bf16 centers
    float* csq = (float*)((char*)d_ws + (size_t)K_CTR * D_DIM * 2);   // 4 KB c_sq

    rbf_prep<<<K_CTR / 4, 256, 0, stream>>>(centers, cbf, csq);
    rbf_main<<<B_ROWS / BM, 512, 0, stream>>>(x, cbf, csq, betas, out);
}

// Round 5
// 35.484 us; speedup vs baseline: 1.4843x; 1.4843x over previous
//
#include <hip/hip_runtime.h>
#include <hip/hip_bf16.h>
#include <stdint.h>

#define D_DIM 256
#define K_CTR 1024
#define B_ROWS 16384
#define BM 32

typedef __bf16 bf16x8 __attribute__((ext_vector_type(8)));
typedef float f32x4 __attribute__((ext_vector_type(4)));

static __device__ __forceinline__ unsigned short f2bf(float f) {
    return __builtin_bit_cast(unsigned short, __float2bfloat16(f));
}

// Prep: centers f32 -> bf16 fragment-major + c_sq f32. 4 rows/block.
// Chunk (colgrp, kk, hk, col&15) at byte colgrp*8192 + kk*1024 + hk*256 + (col&15)*16
// -> main's wave B-load (lane l) is one contiguous 1KB dwordx4 at l*16.
__global__ __launch_bounds__(256) void rbf_prep(const float* __restrict__ centers,
                                                unsigned short* __restrict__ cbf,
                                                float* __restrict__ csq) {
    const int w = threadIdx.x >> 6;
    const int l = threadIdx.x & 63;
    const int row = blockIdx.x * 4 + w;
    const float4 v = *reinterpret_cast<const float4*>(centers + row * D_DIM + l * 4);
    float s = v.x * v.x + v.y * v.y + v.z * v.z + v.w * v.w;
    ushort4 p;
    p.x = f2bf(v.x); p.y = f2bf(v.y); p.z = f2bf(v.z); p.w = f2bf(v.w);
    char* dst = reinterpret_cast<char*>(cbf)
              + (row >> 4) * 8192 + (l >> 3) * 1024 + ((l >> 1) & 3) * 256
              + (row & 15) * 16 + (l & 1) * 8;
    *reinterpret_cast<ushort4*>(dst) = p;
    #pragma unroll
    for (int off = 1; off < 64; off <<= 1) s += __shfl_xor(s, off);
    if (l == 0) csq[row] = s;
}

// Main: 512 thr (8 waves), block = 32 rows x 1024 cols. 4 column-quarters of 256.
// Per quarter: wave w computes 32 rows x 32 cols (wc slice), results staged in a
// 32KB LDS buffer, then stored as SINGLE-SEGMENT contiguous 1KB wave stores
// (fill-kernel-identical write stream).
__global__ __launch_bounds__(512, 4) void rbf_main(const float* __restrict__ x,
                                                   const unsigned short* __restrict__ cbf,
                                                   const float* __restrict__ csq,
                                                   const float* __restrict__ betas,
                                                   float* __restrict__ out) {
    __shared__ __align__(16) unsigned short As[BM * D_DIM];  // 16 KB, XOR-swizzled
    __shared__ __align__(16) float obuf[BM * 256];           // 32 KB output slice, swizzled
    __shared__ float xs_lds[BM];

    const int tid = threadIdx.x;
    const int w = tid >> 6;
    const int l = tid & 63;
    // XCD-chunked bijective swizzle: XCD i gets 64 consecutive strips
    const int strip = (blockIdx.x & 7) * 64 + (blockIdx.x >> 3);
    const int row0 = strip * BM;

    // ---- Stage A strip (bf16, swizzled) + x_sq ----
    #pragma unroll
    for (int i = 0; i < 4; ++i) {
        const int r = i * 8 + w;
        const float4 v = *reinterpret_cast<const float4*>(x + (row0 + r) * D_DIM + l * 4);
        float s = v.x * v.x + v.y * v.y + v.z * v.z + v.w * v.w;
        ushort4 p;
        p.x = f2bf(v.x); p.y = f2bf(v.y); p.z = f2bf(v.z); p.w = f2bf(v.w);
        const unsigned boff = (unsigned)((r * 512 + l * 8) ^ ((r & 7) << 4));
        *reinterpret_cast<ushort4*>(reinterpret_cast<char*>(As) + boff) = p;
        #pragma unroll
        for (int off = 1; off < 64; off <<= 1) s += __shfl_xor(s, off);
        if (l == 0) xs_lds[r] = s;
    }
    __syncthreads();

    const int hk = l >> 4;
    const int lr = l & 15;
    const float xs0 = xs_lds[lr];
    const float xs1 = xs_lds[16 + lr];
    const char* bwave = reinterpret_cast<const char*>(cbf) + l * 16;

    for (int ct = 0; ct < 4; ++ct) {
        const int colq = ct * 256;            // quarter base
        const int colw = colq + w * 32;       // this wave's 32 cols
        const char* bbase = bwave + (colw >> 4) * 8192;

        // Burst B for this wave's 32 cols (16 x 1KB coalesced; B read once/block)
        bf16x8 b[2][8];
        #pragma unroll
        for (int kk = 0; kk < 8; ++kk)
            #pragma unroll
            for (int n = 0; n < 2; ++n)
                b[n][kk] = *reinterpret_cast<const bf16x8*>(bbase + n * 8192 + kk * 1024);

        // MFMA: 4 independent chains (m2 x n2), A from LDS per kk
        f32x4 acc[2][2] = {};
        #pragma unroll
        for (int kk = 0; kk < 8; ++kk) {
            const unsigned o0 = (unsigned)((lr * 512 + kk * 64 + hk * 16) ^ ((lr & 7) << 4));
            const unsigned o1 = (unsigned)(((16 + lr) * 512 + kk * 64 + hk * 16) ^ ((lr & 7) << 4));
            const bf16x8 a0 = *reinterpret_cast<const bf16x8*>(reinterpret_cast<const char*>(As) + o0);
            const bf16x8 a1 = *reinterpret_cast<const bf16x8*>(reinterpret_cast<const char*>(As) + o1);
            #pragma unroll
            for (int n = 0; n < 2; ++n) {
                acc[0][n] = __builtin_amdgcn_mfma_f32_16x16x32_bf16(b[n][kk], a0, acc[0][n], 0, 0, 0);
                acc[1][n] = __builtin_amdgcn_mfma_f32_16x16x32_bf16(b[n][kk], a1, acc[1][n], 0, 0, 0);
            }
        }

        // Epilogue: exp(-beta*(xsq+csq-2*cross)) -> swizzled LDS obuf
        #pragma unroll
        for (int n = 0; n < 2; ++n) {
            const int cl = w * 32 + n * 16 + hk * 4;   // col within quarter
            const f32x4 cs = *reinterpret_cast<const f32x4*>(csq + colq + cl);
            const f32x4 bt = *reinterpret_cast<const f32x4*>(betas + colq + cl);
            #pragma unroll
            for (int m = 0; m < 2; ++m) {
                const int r = m * 16 + lr;
                const float xs = m ? xs1 : xs0;
                f32x4 rv;
                #pragma unroll
                for (int j = 0; j < 4; ++j)
                    rv[j] = __expf(-bt[j] * (xs + cs[j] - 2.0f * acc[m][n][j]));
                *reinterpret_cast<f32x4*>(reinterpret_cast<char*>(obuf)
                    + r * 1024 + ((cl * 4) ^ ((r & 7) << 4))) = rv;
            }
        }
        __syncthreads();

        // Linear store: wave w -> rows 4w..4w+3; each instr = ONE contiguous 1KB segment
        #pragma unroll
        for (int i = 0; i < 4; ++i) {
            const int r = w * 4 + i;
            const f32x4 v = *reinterpret_cast<const f32x4*>(reinterpret_cast<const char*>(obuf)
                    + r * 1024 + ((l * 16) ^ ((r & 7) << 4)));
            *reinterpret_cast<f32x4*>(out + (size_t)(row0 + r) * K_CTR + colq + l * 4) = v;
        }
        __syncthreads();
    }
}

extern "C" void kernel_launch(void* const* d_in, const int* in_sizes, int n_in,
                              void* d_out, int out_size, void* d_ws, size_t ws_size,
                              hipStream_t stream) {
    const float* x       = (const float*)d_in[0];
    const float* centers = (const float*)d_in[1];
    const float* betas   = (const float*)d_in[2];
    float* out = (float*)d_out;

    unsigned short* cbf = (unsigned short*)d_ws;                      // 512 KB fragment-major bf16 centers
    float* csq = (float*)((char*)d_ws + (size_t)K_CTR * D_DIM * 2);   // 4 KB c_sq

    rbf_prep<<<K_CTR / 4, 256, 0, stream>>>(centers, cbf, csq);
    rbf_main<<<B_ROWS / BM, 512, 0, stream>>>(x, cbf, csq, betas, out);
}

// Round 6
// 27.983 us; speedup vs baseline: 1.8822x; 1.2681x over previous
//
#include <hip/hip_runtime.h>
#include <stdint.h>

#define D_DIM 256
#define K_CTR 1024
#define B_ROWS 16384
#define BM 32

typedef float f32x4 __attribute__((ext_vector_type(4)));
typedef long long i64x2 __attribute__((ext_vector_type(2)));

// Pack 4 f32 -> 4 fp8 e4m3 bytes (OCP, HW cvt).
static __device__ __forceinline__ unsigned cvt4_fp8(const float4 v) {
    int r = __builtin_amdgcn_cvt_pk_fp8_f32(v.x, v.y, 0, false);   // bytes 0-1
    r = __builtin_amdgcn_cvt_pk_fp8_f32(v.z, v.w, r, true);        // bytes 2-3
    return (unsigned)r;
}

// Prep: centers f32 -> fp8 fragment-major (pair-interleaved) + c_sq f32.
// Value c[col][d] (kk=d>>5, hk=(d>>3)&3, j=d&7, p=kk>>1, e=kk&1) at byte:
//   (col>>4)*4096 + p*1024 + (hk*16 + (col&15))*16 + e*8 + j
// -> main's wave load (lane l=hk*16+lr) at p*1024 + l*16 is one dwordx4
//    holding frags kk=2p (bytes 0-7) and kk=2p+1 (bytes 8-15), 1KB/wave-instr.
__global__ __launch_bounds__(256) void rbf_prep(const float* __restrict__ centers,
                                                unsigned char* __restrict__ cbf,
                                                float* __restrict__ csq) {
    const int w = threadIdx.x >> 6;
    const int l = threadIdx.x & 63;
    const int c0 = blockIdx.x * 4 + w;
    const float4 v = *reinterpret_cast<const float4*>(centers + c0 * D_DIM + l * 4);
    float s = v.x * v.x + v.y * v.y + v.z * v.z + v.w * v.w;
    const unsigned u = cvt4_fp8(v);
    // d = 4l..4l+3: kk=l>>3, p=l>>4, e=(l>>3)&1, hk=(l>>1)&3, j=(l&1)*4
    const unsigned off = (unsigned)((c0 >> 4) * 4096 + (l >> 4) * 1024
                       + (((l >> 1) & 3) * 16 + (c0 & 15)) * 16
                       + ((l >> 3) & 1) * 8 + (l & 1) * 4);
    *reinterpret_cast<unsigned*>(cbf + off) = u;
    #pragma unroll
    for (int off2 = 1; off2 < 64; off2 <<= 1) s += __shfl_xor(s, off2);
    if (l == 0) csq[c0] = s;
}

// Main: 512 thr (8 waves), block = 32 rows x 1024 cols, 4 quarters of 256 cols.
// A (x) staged once in LDS as fp8 (pair-interleaved, XOR-swizzled), hoisted to
// registers once. Per quarter: 8x 1KB B loads, 32 fp8 MFMAs, exp epilogue ->
// double-buffered 32KB obuf (1 barrier), then single-segment 1KB wave stores.
__global__ __launch_bounds__(512, 4) void rbf_main(const float* __restrict__ x,
                                                   const unsigned char* __restrict__ cbf,
                                                   const float* __restrict__ csq,
                                                   const float* __restrict__ betas,
                                                   float* __restrict__ out) {
    __shared__ __align__(16) unsigned char As[BM * D_DIM];   // 8 KB fp8, swizzled
    __shared__ __align__(16) float obuf[2][BM * 256];        // 2 x 32 KB
    __shared__ float xs_lds[BM];

    const int tid = threadIdx.x;
    const int w = tid >> 6;
    const int l = tid & 63;
    // XCD-chunked bijective swizzle (512 = 8*64)
    const int strip = (blockIdx.x & 7) * 64 + (blockIdx.x >> 3);
    const int row0 = strip * BM;

    // ---- Stage A strip as fp8 + x_sq. Row layout: pos(d)=p*64+hk*16+e*8+j,
    //      swizzled byte = r*256 + (pos ^ ((r&7)<<4)). Lane l covers d=4l..4l+3:
    //      pos = (l>>4)*64 + ((l>>1)&3)*16 + ((l>>3)&1)*8 + (l&1)*4.
    #pragma unroll
    for (int i = 0; i < 4; ++i) {
        const int r = i * 8 + w;
        const float4 v = *reinterpret_cast<const float4*>(x + (size_t)(row0 + r) * D_DIM + l * 4);
        float s = v.x * v.x + v.y * v.y + v.z * v.z + v.w * v.w;
        const unsigned u = cvt4_fp8(v);
        const unsigned pos = (unsigned)((l >> 4) * 64 + ((l >> 1) & 3) * 16
                           + ((l >> 3) & 1) * 8 + (l & 1) * 4);
        *reinterpret_cast<unsigned*>(As + r * 256 + (pos ^ ((unsigned)(r & 7) << 4))) = u;
        #pragma unroll
        for (int off = 1; off < 64; off <<= 1) s += __shfl_xor(s, off);
        if (l == 0) xs_lds[r] = s;
    }
    __syncthreads();

    const int hk = l >> 4;
    const int lr = l & 15;

    // ---- Hoist A frags once: 8 ds_read_b128 (m 0..1 x p 0..3), 32 VGPR ----
    i64x2 a[2][4];
    #pragma unroll
    for (int m = 0; m < 2; ++m) {
        const int r = m * 16 + lr;
        #pragma unroll
        for (int p = 0; p < 4; ++p)
            a[m][p] = *reinterpret_cast<const i64x2*>(
                As + r * 256 + ((unsigned)(p * 64 + hk * 16) ^ ((unsigned)(lr & 7) << 4)));
    }
    const float xs0 = xs_lds[lr];
    const float xs1 = xs_lds[16 + lr];

    #pragma unroll 1
    for (int ct = 0; ct < 4; ++ct) {
        const int colq = ct * 256;
        const int colw = colq + w * 32;
        const unsigned char* bbase = cbf + (colw >> 4) * 4096 + l * 16;

        // Burst B: 8 x 1KB coalesced dwordx4 (each = 2 fp8 frags)
        i64x2 b[2][4];
        #pragma unroll
        for (int p = 0; p < 4; ++p)
            #pragma unroll
            for (int n = 0; n < 2; ++n)
                b[n][p] = *reinterpret_cast<const i64x2*>(bbase + n * 4096 + p * 1024);

        // 32 MFMAs, 4 independent acc chains
        f32x4 acc[2][2] = {};
        #pragma unroll
        for (int p = 0; p < 4; ++p)
            #pragma unroll
            for (int n = 0; n < 2; ++n)
                #pragma unroll
                for (int m = 0; m < 2; ++m) {
                    acc[m][n] = __builtin_amdgcn_mfma_f32_16x16x32_fp8_fp8(b[n][p][0], a[m][p][0], acc[m][n], 0, 0, 0);
                    acc[m][n] = __builtin_amdgcn_mfma_f32_16x16x32_fp8_fp8(b[n][p][1], a[m][p][1], acc[m][n], 0, 0, 0);
                }

        // Epilogue -> swizzled obuf[ct&1]
        float* ob = obuf[ct & 1];
        #pragma unroll
        for (int n = 0; n < 2; ++n) {
            const int cl = w * 32 + n * 16 + hk * 4;
            const f32x4 cs = *reinterpret_cast<const f32x4*>(csq + colq + cl);
            const f32x4 bt = *reinterpret_cast<const f32x4*>(betas + colq + cl);
            #pragma unroll
            for (int m = 0; m < 2; ++m) {
                const int r = m * 16 + lr;
                const float xsv = m ? xs1 : xs0;
                f32x4 rv;
                #pragma unroll
                for (int j = 0; j < 4; ++j)
                    rv[j] = __expf(-bt[j] * (xsv + cs[j] - 2.0f * acc[m][n][j]));
                *reinterpret_cast<f32x4*>(reinterpret_cast<char*>(ob)
                    + r * 1024 + ((unsigned)(cl * 4) ^ ((unsigned)(r & 7) << 4))) = rv;
            }
        }
        __syncthreads();

        // Single-segment contiguous 1KB wave stores: wave w -> rows 4w..4w+3
        #pragma unroll
        for (int i = 0; i < 4; ++i) {
            const int r = w * 4 + i;
            const f32x4 v = *reinterpret_cast<const f32x4*>(reinterpret_cast<const char*>(ob)
                    + r * 1024 + ((unsigned)(l * 16) ^ ((unsigned)(r & 7) << 4)));
            *reinterpret_cast<f32x4*>(out + (size_t)(row0 + r) * K_CTR + colq + l * 4) = v;
        }
    }
}

extern "C" void kernel_launch(void* const* d_in, const int* in_sizes, int n_in,
                              void* d_out, int out_size, void* d_ws, size_t ws_size,
                              hipStream_t stream) {
    const float* x       = (const float*)d_in[0];
    const float* centers = (const float*)d_in[1];
    const float* betas   = (const float*)d_in[2];
    float* out = (float*)d_out;

    unsigned char* cbf = (unsigned char*)d_ws;                        // 256 KB fp8 fragment-major centers
    float* csq = (float*)((char*)d_ws + (size_t)K_CTR * D_DIM);       // 4 KB c_sq

    rbf_prep<<<K_CTR / 4, 256, 0, stream>>>(centers, cbf, csq);
    rbf_main<<<B_ROWS / BM, 512, 0, stream>>>(x, cbf, csq, betas, out);
}

// Round 7
// 27.551 us; speedup vs baseline: 1.9118x; 1.0157x over previous
//
#include <hip/hip_runtime.h>
#include <stdint.h>

#define D_DIM 256
#define K_CTR 1024
#define B_ROWS 16384
#define BM 32

typedef float f32x4 __attribute__((ext_vector_type(4)));
typedef long long i64x2 __attribute__((ext_vector_type(2)));

// Pack 4 f32 -> 4 fp8 e4m3 bytes (OCP, HW cvt).
static __device__ __forceinline__ unsigned cvt4_fp8(const float4 v) {
    int r = __builtin_amdgcn_cvt_pk_fp8_f32(v.x, v.y, 0, false);   // bytes 0-1
    r = __builtin_amdgcn_cvt_pk_fp8_f32(v.z, v.w, r, true);        // bytes 2-3
    return (unsigned)r;
}

// Prep: centers f32 -> fp8 fragment-major (pair-interleaved) + c_sq f32.
// Value c[col][d] (kk=d>>5, p=kk>>1, e=kk&1, hk=(d>>3)&3, j=d&7) at byte:
//   (col>>4)*4096 + p*1024 + (hk*16 + (col&15))*16 + e*8 + j
// -> main's wave load (lane l) at p*1024 + l*16 is one 1KB dwordx4 holding
//    frags kk=2p (bytes 0-7) and kk=2p+1 (bytes 8-15).
__global__ __launch_bounds__(256) void rbf_prep(const float* __restrict__ centers,
                                                unsigned char* __restrict__ cbf,
                                                float* __restrict__ csq) {
    const int w = threadIdx.x >> 6;
    const int l = threadIdx.x & 63;
    const int c0 = blockIdx.x * 4 + w;
    const float4 v = *reinterpret_cast<const float4*>(centers + c0 * D_DIM + l * 4);
    float s = v.x * v.x + v.y * v.y + v.z * v.z + v.w * v.w;
    const unsigned u = cvt4_fp8(v);
    const unsigned off = (unsigned)((c0 >> 4) * 4096 + (l >> 4) * 1024
                       + (((l >> 1) & 3) * 16 + (c0 & 15)) * 16
                       + ((l >> 3) & 1) * 8 + (l & 1) * 4);
    *reinterpret_cast<unsigned*>(cbf + off) = u;
    #pragma unroll
    for (int off2 = 1; off2 < 64; off2 <<= 1) s += __shfl_xor(s, off2);
    if (l == 0) csq[c0] = s;
}

// Main: 512 thr (8 waves), block = 32 rows x 1024 cols, 4 quarters of 256 cols.
// Software-pipelined: B(ct+1) global loads issue BEFORE MFMA(ct) so their
// latency hides under compute+store of the current quarter (T14).
__global__ __launch_bounds__(512, 4) void rbf_main(const float* __restrict__ x,
                                                   const unsigned char* __restrict__ cbf,
                                                   const float* __restrict__ csq,
                                                   const float* __restrict__ betas,
                                                   float* __restrict__ out) {
    __shared__ __align__(16) unsigned char As[BM * D_DIM];   // 8 KB fp8, swizzled
    __shared__ __align__(16) float obuf[2][BM * 256];        // 2 x 32 KB
    __shared__ float xs_lds[BM];

    const int tid = threadIdx.x;
    const int w = tid >> 6;
    const int l = tid & 63;
    // XCD-chunked bijective swizzle (512 = 8*64)
    const int strip = (blockIdx.x & 7) * 64 + (blockIdx.x >> 3);
    const int row0 = strip * BM;

    // ---- Stage A strip as fp8 + x_sq ----
    #pragma unroll
    for (int i = 0; i < 4; ++i) {
        const int r = i * 8 + w;
        const float4 v = *reinterpret_cast<const float4*>(x + (size_t)(row0 + r) * D_DIM + l * 4);
        float s = v.x * v.x + v.y * v.y + v.z * v.z + v.w * v.w;
        const unsigned u = cvt4_fp8(v);
        const unsigned pos = (unsigned)((l >> 4) * 64 + ((l >> 1) & 3) * 16
                           + ((l >> 3) & 1) * 8 + (l & 1) * 4);
        *reinterpret_cast<unsigned*>(As + r * 256 + (pos ^ ((unsigned)(r & 7) << 4))) = u;
        #pragma unroll
        for (int off = 1; off < 64; off <<= 1) s += __shfl_xor(s, off);
        if (l == 0) xs_lds[r] = s;
    }

    const int hk = l >> 4;
    const int lr = l & 15;
    const unsigned char* bwave = cbf + l * 16;

    // ---- Issue B(quarter 0) BEFORE the barrier: latency hides under drain ----
    i64x2 b0[2][4], b1[2][4];
    {
        const unsigned char* bbase = bwave + ((w * 32) >> 4) * 4096;
        #pragma unroll
        for (int p = 0; p < 4; ++p)
            #pragma unroll
            for (int n = 0; n < 2; ++n)
                b0[n][p] = *reinterpret_cast<const i64x2*>(bbase + n * 4096 + p * 1024);
    }
    __syncthreads();

    // ---- Hoist A frags once: 8 ds_read_b128 ----
    i64x2 a[2][4];
    #pragma unroll
    for (int m = 0; m < 2; ++m) {
        const int r = m * 16 + lr;
        #pragma unroll
        for (int p = 0; p < 4; ++p)
            a[m][p] = *reinterpret_cast<const i64x2*>(
                As + r * 256 + ((unsigned)(p * 64 + hk * 16) ^ ((unsigned)(lr & 7) << 4)));
    }
    const float xs0 = xs_lds[lr];
    const float xs1 = xs_lds[16 + lr];
    const float LOG2E = 1.4426950408889634f;

    #pragma unroll
    for (int ct = 0; ct < 4; ++ct) {
        const int colq = ct * 256;
        const i64x2 (&bc)[2][4] = (ct & 1) ? b1 : b0;
        i64x2 (&bn)[2][4] = (ct & 1) ? b0 : b1;

        // ---- Prefetch B(ct+1): issue BEFORE MFMA so MFMA+epilogue+store hide it ----
        if (ct < 3) {
            const unsigned char* bbase = bwave + (((ct + 1) * 256 + w * 32) >> 4) * 4096;
            #pragma unroll
            for (int p = 0; p < 4; ++p)
                #pragma unroll
                for (int n = 0; n < 2; ++n)
                    bn[n][p] = *reinterpret_cast<const i64x2*>(bbase + n * 4096 + p * 1024);
        }

        // ---- 32 MFMAs, 4 independent acc chains ----
        f32x4 acc[2][2] = {};
        #pragma unroll
        for (int p = 0; p < 4; ++p)
            #pragma unroll
            for (int n = 0; n < 2; ++n)
                #pragma unroll
                for (int m = 0; m < 2; ++m) {
                    acc[m][n] = __builtin_amdgcn_mfma_f32_16x16x32_fp8_fp8(bc[n][p][0], a[m][p][0], acc[m][n], 0, 0, 0);
                    acc[m][n] = __builtin_amdgcn_mfma_f32_16x16x32_fp8_fp8(bc[n][p][1], a[m][p][1], acc[m][n], 0, 0, 0);
                }

        // ---- Epilogue: exp2(fma(2*bt*log2e, acc, -bt*log2e*(xs+cs))) -> obuf ----
        float* ob = obuf[ct & 1];
        #pragma unroll
        for (int n = 0; n < 2; ++n) {
            const int cl = w * 32 + n * 16 + hk * 4;
            const f32x4 cs = *reinterpret_cast<const f32x4*>(csq + colq + cl);
            const f32x4 bt = *reinterpret_cast<const f32x4*>(betas + colq + cl);
            f32x4 btl2, coef2, base;
            #pragma unroll
            for (int j = 0; j < 4; ++j) {
                btl2[j] = bt[j] * LOG2E;
                coef2[j] = btl2[j] + btl2[j];
                base[j] = -btl2[j] * cs[j];
            }
            #pragma unroll
            for (int m = 0; m < 2; ++m) {
                const int r = m * 16 + lr;
                const float xsv = m ? xs1 : xs0;
                f32x4 rv;
                #pragma unroll
                for (int j = 0; j < 4; ++j) {
                    const float c0 = __builtin_fmaf(-btl2[j], xsv, base[j]);
                    rv[j] = __builtin_exp2f(__builtin_fmaf(coef2[j], acc[m][n][j], c0));
                }
                *reinterpret_cast<f32x4*>(reinterpret_cast<char*>(ob)
                    + r * 1024 + ((unsigned)(cl * 4) ^ ((unsigned)(r & 7) << 4))) = rv;
            }
        }
        __syncthreads();

        // ---- Single-segment contiguous 1KB wave stores: wave w -> rows 4w..4w+3 ----
        #pragma unroll
        for (int i = 0; i < 4; ++i) {
            const int r = w * 4 + i;
            const f32x4 v = *reinterpret_cast<const f32x4*>(reinterpret_cast<const char*>(ob)
                    + r * 1024 + ((unsigned)(l * 16) ^ ((unsigned)(r & 7) << 4)));
            *reinterpret_cast<f32x4*>(out + (size_t)(row0 + r) * K_CTR + colq + l * 4) = v;
        }
    }
}

extern "C" void kernel_launch(void* const* d_in, const int* in_sizes, int n_in,
                              void* d_out, int out_size, void* d_ws, size_t ws_size,
                              hipStream_t stream) {
    const float* x       = (const float*)d_in[0];
    const float* centers = (const float*)d_in[1];
    const float* betas   = (const float*)d_in[2];
    float* out = (float*)d_out;

    unsigned char* cbf = (unsigned char*)d_ws;                        // 256 KB fp8 fragment-major centers
    float* csq = (float*)((char*)d_ws + (size_t)K_CTR * D_DIM);       // 4 KB c_sq

    rbf_prep<<<K_CTR / 4, 256, 0, stream>>>(centers, cbf, csq);
    rbf_main<<<B_ROWS / BM, 512, 0, stream>>>(x, cbf, csq, betas, out);
}